// Round 7
// baseline (229.003 us; speedup 1.0000x reference)
//
#include <hip/hip_runtime.h>
#include <math.h>

#define HDIM 4096
#define THREADS 256
#define CHUNK 4          // HDIM / (THREADS * 4) float4 chunks per thread
#define EPSV 1e-6f

typedef float f4 __attribute__((ext_vector_type(4)));

__device__ __forceinline__ float waveSum(float v) {
    #pragma unroll
    for (int o = 32; o > 0; o >>= 1) v += __shfl_xor(v, o);
    return v;
}
__device__ __forceinline__ float waveMax(float v) {
    #pragma unroll
    for (int o = 32; o > 0; o >>= 1) v = fmaxf(v, __shfl_xor(v, o));
    return v;
}

// One block per row of 4096. R6 structure (chunk rotation) with PLAIN stores:
// NT stores bypass L2/LLC write staging and dribble 64B writes into the HBM
// queues; plain stores let dirty lines batch-evict (fillBuffer hits 6.8 TB/s
// this way). Full-line writes -> no RFO fetch traffic added.
__global__ __launch_bounds__(THREADS) void fused_add_rmsnorm_quant(
    const float* __restrict__ x1, const float* __restrict__ x2,
    const float* __restrict__ w,  const float* __restrict__ sm,
    float* __restrict__ out, const long long N, const long long R)
{
    __shared__ float redS[4];
    __shared__ float redW[4];
    __shared__ float redM[4];

    const int tid  = threadIdx.x;
    const int wave = tid >> 6;
    const int lane = tid & 63;
    const long long row  = blockIdx.x;
    const long long base = row * (long long)HDIM;

    // ---- output layout: 10 outputs concatenated flat, all f32 ----
    float* out_q   = out;                 // yOut        [N]
    float* out_x   = out + N;             // xOut        [N]
    float* out_s1  = out + 2 * N;         // scale1Out   [R]
    float* out_y   = out + 2 * N + R;     // y1_flat     [N]
    float* out_xb  = out + 3 * N + R;     // xOut1       [N]
    float* out_q2  = out + 4 * N + R;     // yOut2       [N]
    float* out_x3  = out + 5 * N + 2 * R; // xOut3       [N]
    float* out_q3  = out + 6 * N + 2 * R; // yOut3       [N]
    float* out_s2  = out + 5 * N + R;     // scale1Out2  [R]
    float* out_s3  = out + 7 * N + 2 * R; // scale1Out3  [R]

    f4 xv[CHUNK];   // x1+x2 — the only state held across the barrier

    // ---- pass 1: load, add, row statistics ----
    float ss = 0.f, mW = 0.f, mSm = 0.f;
    #pragma unroll
    for (int c = 0; c < CHUNK; ++c) {
        const int col = c * (THREADS * 4) + tid * 4;
        const long long idx = base + col;
        const f4 a = __builtin_nontemporal_load(
            reinterpret_cast<const f4*>(x1 + idx));
        const f4 b = __builtin_nontemporal_load(
            reinterpret_cast<const f4*>(x2 + idx));
        const f4 wv  = *reinterpret_cast<const f4*>(w  + col);
        const f4 smv = *reinterpret_cast<const f4*>(sm + col);
        const f4 x = a + b;
        xv[c] = x;
        #pragma unroll
        for (int j = 0; j < 4; ++j) {
            const float t = x[j] * wv[j];     // y = t*inv
            ss += x[j] * x[j];
            mW  = fmaxf(mW,  fabsf(t));
            mSm = fmaxf(mSm, fabsf(t * smv[j]));
        }
    }

    // ---- x-streams, chunk-rotated per stream (all xv ready) ----
    #pragma unroll
    for (int c = 0; c < CHUNK; ++c) {
        const int c0 = c, c1 = (c + 1) & 3, c2 = (c + 2) & 3;
        *reinterpret_cast<f4*>(out_x  + base + c0 * (THREADS * 4) + tid * 4) = xv[c0];
        *reinterpret_cast<f4*>(out_xb + base + c1 * (THREADS * 4) + tid * 4) = xv[c1];
        *reinterpret_cast<f4*>(out_x3 + base + c2 * (THREADS * 4) + tid * 4) = xv[c2];
    }

    ss  = waveSum(ss);
    mW  = waveMax(mW);
    mSm = waveMax(mSm);
    if (lane == 0) { redS[wave] = ss; redW[wave] = mW; redM[wave] = mSm; }
    __syncthreads();
    ss  = (redS[0] + redS[1]) + (redS[2] + redS[3]);
    mW  = fmaxf(fmaxf(redW[0], redW[1]), fmaxf(redW[2], redW[3]));
    mSm = fmaxf(fmaxf(redM[0], redM[1]), fmaxf(redM[2], redM[3]));

    const float inv    = 1.0f / sqrtf(ss * (1.0f / HDIM) + EPSV);
    const float scale1 = (inv * mSm) * (1.0f / 127.0f);
    const float scale3 = (inv * mW)  * (1.0f / 127.0f);
    const float rs1 = 1.0f / scale1;
    const float rs3 = 1.0f / scale3;

    // ---- pass 2: 4 streams, chunk-rotated per stream ----
    #pragma unroll
    for (int c = 0; c < CHUNK; ++c) {
        const int cq  = c;
        const int cy  = (c + 1) & 3;
        const int cq2 = (c + 2) & 3;
        const int cq3 = (c + 3) & 3;

        {   // q @ chunk cq
            const int col = cq * (THREADS * 4) + tid * 4;
            const f4 wv  = *reinterpret_cast<const f4*>(w  + col);
            const f4 smv = *reinterpret_cast<const f4*>(sm + col);
            f4 qf;
            #pragma unroll
            for (int j = 0; j < 4; ++j)
                qf[j] = rintf(xv[cq][j] * inv * wv[j] * smv[j] * rs1);
            *reinterpret_cast<f4*>(out_q + base + col) = qf;
        }
        {   // y @ chunk cy
            const int col = cy * (THREADS * 4) + tid * 4;
            const f4 wv = *reinterpret_cast<const f4*>(w + col);
            f4 yq;
            #pragma unroll
            for (int j = 0; j < 4; ++j)
                yq[j] = xv[cy][j] * inv * wv[j];
            *reinterpret_cast<f4*>(out_y + base + col) = yq;
        }
        {   // q2 @ chunk cq2
            const int col = cq2 * (THREADS * 4) + tid * 4;
            const f4 wv  = *reinterpret_cast<const f4*>(w  + col);
            const f4 smv = *reinterpret_cast<const f4*>(sm + col);
            f4 qf;
            #pragma unroll
            for (int j = 0; j < 4; ++j)
                qf[j] = rintf(xv[cq2][j] * inv * wv[j] * smv[j] * rs1);
            *reinterpret_cast<f4*>(out_q2 + base + col) = qf;
        }
        {   // q3 @ chunk cq3
            const int col = cq3 * (THREADS * 4) + tid * 4;
            const f4 wv = *reinterpret_cast<const f4*>(w + col);
            f4 q3;
            #pragma unroll
            for (int j = 0; j < 4; ++j)
                q3[j] = rintf(xv[cq3][j] * inv * wv[j] * rs3);
            *reinterpret_cast<f4*>(out_q3 + base + col) = q3;
        }
    }

    if (tid == 0) {
        out_s1[row] = scale1;
        out_s2[row] = scale1;
        out_s3[row] = scale3;
    }
}

extern "C" void kernel_launch(void* const* d_in, const int* in_sizes, int n_in,
                              void* d_out, int out_size, void* d_ws, size_t ws_size,
                              hipStream_t stream) {
    const float* x1 = (const float*)d_in[0];
    const float* x2 = (const float*)d_in[1];
    const float* w  = (const float*)d_in[2];
    const float* sm = (const float*)d_in[3];
    float* out = (float*)d_out;

    const long long N = (long long)in_sizes[0];   // 2*4096*4096
    const long long R = N / HDIM;                 // 8192 rows

    fused_add_rmsnorm_quant<<<dim3((unsigned)R), dim3(THREADS), 0, stream>>>(
        x1, x2, w, sm, out, N, R);
}